// Round 4
// baseline (1326.192 us; speedup 1.0000x reference)
//
#include <hip/hip_runtime.h>
#include <cstdint>
#include <cstddef>

typedef __bf16 bf16_t;
typedef __attribute__((ext_vector_type(8))) __bf16 bf16x8;
typedef __attribute__((ext_vector_type(4))) __bf16 bf16x4;
typedef __attribute__((ext_vector_type(4))) float floatx4;

#define SB0 __builtin_amdgcn_sched_barrier(0)
#define LGKM(N)                                             \
  do {                                                      \
    asm volatile("s_waitcnt lgkmcnt(" #N ")" ::: "memory"); \
    SB0;                                                    \
  } while (0)

// ---------------------------------------------------------------------------
// async 16B global -> LDS copy (direct-to-LDS DMA, no VGPR round trip).
__device__ __forceinline__ void cp16(const void* g, void* l) {
  __builtin_amdgcn_global_load_lds(
      (const __attribute__((address_space(1))) void*)(uintptr_t)g,
      (__attribute__((address_space(3))) void*)(uintptr_t)l, 16, 0, 0);
}

// stage one 16 KB half-tile (256 rows x 32 k bf16): 2 issues x 512 thr x 16 B.
__device__ __forceinline__ void stage_half(const bf16_t* p, int K, char* dst,
                                           int tid) {
  cp16(p, dst + tid * 16);
  cp16(p + (size_t)128 * K, dst + 8192 + tid * 16);
}

// ---------------------------------------------------------------------------
// Fused prep: x->bf16 cvt | 4x W^T assembly | 4x bias row. One launch.
struct PrepArgs {
  const float* x;
  bf16_t* xb;
  const float* M[4];
  const float* u[4];
  const float* v[4];
  const float* e[4];
  bf16_t* Wt[4];
  float* bias[4];
};

__global__ __launch_bounds__(256) void prep_all(PrepArgs a) {
  __shared__ float tile[32][33];
  const int tx = threadIdx.x, ty = threadIdx.y;
  const int tid = ty * 32 + tx;
  int bid = blockIdx.x;

  if (bid < 16384) {  // ---- cvt: 8192x2048 fp32 -> bf16, float4-vectorized
    const int i = bid * 256 + tid;
    float4 f = ((const float4*)a.x)[i];
    bf16x4 o;
    o[0] = (bf16_t)f.x; o[1] = (bf16_t)f.y; o[2] = (bf16_t)f.z; o[3] = (bf16_t)f.w;
    ((bf16x4*)a.xb)[i] = o;
    return;
  }
  bid -= 16384;

  if (bid >= 49152) {  // ---- bias rows (56 blocks of 256)
    const int b = bid - 49152;
    int layer, base;
    if (b < 16) { layer = 0; base = b; }
    else if (b < 32) { layer = 1; base = b - 16; }
    else if (b < 48) { layer = 2; base = b - 32; }
    else { layer = 3; base = b - 48; }
    const int K = (layer == 0) ? 2048 : 4096;
    const int N = (layer == 3) ? 2048 : 4096;
    const int n = base * 256 + tid;
    if (n < N) {
      const size_t idx = (size_t)K * N + n;
      a.bias[layer][n] = a.M[layer][idx] +
                         __expf(0.5f * a.u[layer][K]) * a.e[layer][idx] *
                             __expf(0.5f * a.v[layer][n]);
    }
    return;
  }

  // ---- W^T tiles: Wt[n][k] = bf16(M[k][n] + exp(.5u[k])*eps[k][n]*exp(.5v[n]))
  int layer, nbx, kby, K, N;
  if (bid < 8192) { layer = 0; K = 2048; N = 4096; nbx = bid & 127; kby = bid >> 7; }
  else if (bid < 24576) { layer = 1; K = 4096; N = 4096; int b = bid - 8192; nbx = b & 127; kby = b >> 7; }
  else if (bid < 40960) { layer = 2; K = 4096; N = 4096; int b = bid - 24576; nbx = b & 127; kby = b >> 7; }
  else { layer = 3; K = 4096; N = 2048; int b = bid - 40960; nbx = b & 63; kby = b >> 6; }
  const float* M = a.M[layer];
  const float* u = a.u[layer];
  const float* v = a.v[layer];
  const float* eps = a.e[layer];
  bf16_t* Wt = a.Wt[layer];
  const int nb = nbx * 32, kb = kby * 32;
  const float sv = __expf(0.5f * v[nb + tx]);
#pragma unroll
  for (int r = 0; r < 4; ++r) {
    const int k = kb + ty + 8 * r;
    const float su = __expf(0.5f * u[k]);
    const size_t idx = (size_t)k * N + nb + tx;
    tile[ty + 8 * r][tx] = M[idx] + su * eps[idx] * sv;
  }
  __syncthreads();
#pragma unroll
  for (int r = 0; r < 4; ++r) {
    const int n = nb + ty + 8 * r;
    Wt[(size_t)n * K + kb + tx] = (bf16_t)tile[tx][ty + 8 * r];
  }
}

// ---------------------------------------------------------------------------
// 256x256 bf16 GEMM, 16x16x32 MFMA (R2's verified conflict-free frag/swizzle),
// ANTI-PHASE schedule: 1 barrier/tile; whole tile t+1 staged at tile start
// (nxt buffer free since the barrier ending tile t-1; vmcnt(0) at tile end is
// ~free: loads issued a full tile ~3000 cyc earlier). Within a tile, waves
// 0-3 process kk0 then kk1; waves 4-7 process kk1 then kk0. Waves w and w+4
// share a SIMD (simd = wave&3), so each SIMD always has one wave reading LDS
// while the other runs MFMAs -> DS pipe and MFMA pipe overlap instead of
// alternating in lockstep (R2/R3's measured serialization).
//
// Per half: issue 12 ds_read_b128 (order pinned: af0,bb0-3 | af1..af7), then
// lgkm(7..0) ladder over 8 MFMA quads, setprio(1) around MFMAs.
// Ledger: all reads of cur drained by each wave's final LGKM(0) before the
// tile-end barrier; staging into nxt only touches the buffer retired at the
// previous tile-end barrier; vmcnt(0)+barrier publishes tile t+1.
__device__ __forceinline__ void half16(const char* Ah, const char* Bh, int aoff,
                                       int boff, floatx4 (&acc)[8][4]) {
  bf16x8 af[8], bb[4];
  af[0] = *(const bf16x8*)(Ah + aoff);
  bb[0] = *(const bf16x8*)(Bh + boff);
  bb[1] = *(const bf16x8*)(Bh + boff + 1024);
  bb[2] = *(const bf16x8*)(Bh + boff + 2048);
  bb[3] = *(const bf16x8*)(Bh + boff + 3072);
  SB0;
  af[1] = *(const bf16x8*)(Ah + aoff + 1024);
  SB0;
  af[2] = *(const bf16x8*)(Ah + aoff + 2048);
  SB0;
  af[3] = *(const bf16x8*)(Ah + aoff + 3072);
  SB0;
  af[4] = *(const bf16x8*)(Ah + aoff + 4096);
  SB0;
  af[5] = *(const bf16x8*)(Ah + aoff + 5120);
  SB0;
  af[6] = *(const bf16x8*)(Ah + aoff + 6144);
  SB0;
  af[7] = *(const bf16x8*)(Ah + aoff + 7168);
  SB0;
  __builtin_amdgcn_s_setprio(1);
  LGKM(7);  // af0 + bb0-3 landed
#pragma unroll
  for (int j = 0; j < 4; ++j)
    acc[0][j] = __builtin_amdgcn_mfma_f32_16x16x32_bf16(bb[j], af[0], acc[0][j], 0, 0, 0);
  LGKM(6);
#pragma unroll
  for (int j = 0; j < 4; ++j)
    acc[1][j] = __builtin_amdgcn_mfma_f32_16x16x32_bf16(bb[j], af[1], acc[1][j], 0, 0, 0);
  LGKM(5);
#pragma unroll
  for (int j = 0; j < 4; ++j)
    acc[2][j] = __builtin_amdgcn_mfma_f32_16x16x32_bf16(bb[j], af[2], acc[2][j], 0, 0, 0);
  LGKM(4);
#pragma unroll
  for (int j = 0; j < 4; ++j)
    acc[3][j] = __builtin_amdgcn_mfma_f32_16x16x32_bf16(bb[j], af[3], acc[3][j], 0, 0, 0);
  LGKM(3);
#pragma unroll
  for (int j = 0; j < 4; ++j)
    acc[4][j] = __builtin_amdgcn_mfma_f32_16x16x32_bf16(bb[j], af[4], acc[4][j], 0, 0, 0);
  LGKM(2);
#pragma unroll
  for (int j = 0; j < 4; ++j)
    acc[5][j] = __builtin_amdgcn_mfma_f32_16x16x32_bf16(bb[j], af[5], acc[5][j], 0, 0, 0);
  LGKM(1);
#pragma unroll
  for (int j = 0; j < 4; ++j)
    acc[6][j] = __builtin_amdgcn_mfma_f32_16x16x32_bf16(bb[j], af[6], acc[6][j], 0, 0, 0);
  LGKM(0);
#pragma unroll
  for (int j = 0; j < 4; ++j)
    acc[7][j] = __builtin_amdgcn_mfma_f32_16x16x32_bf16(bb[j], af[7], acc[7][j], 0, 0, 0);
  __builtin_amdgcn_s_setprio(0);
}

template <int CURB>
__device__ __forceinline__ void ktile(int t, int NT, int K, const bf16_t* gA,
                                      const bf16_t* gB, char* lds, int tid,
                                      int aoff0, int boff0, int firstO,
                                      floatx4 (&acc)[8][4]) {
  constexpr int curO = CURB * 65536;
  constexpr int nxtO = (CURB ^ 1) * 65536;
  // stage whole tile t+1 -> nxt (retired at the barrier that ended tile t-1)
  if (t + 1 < NT) {
    const bf16_t* pa = gA + (size_t)(t + 1) * 64;
    const bf16_t* pb = gB + (size_t)(t + 1) * 64;
    stage_half(pa, K, lds + nxtO, tid);
    stage_half(pa + 32, K, lds + nxtO + 16384, tid);
    stage_half(pb, K, lds + nxtO + 32768, tid);
    stage_half(pb + 32, K, lds + nxtO + 49152, tid);
  }
  SB0;
  // anti-phase: waves 0-3 do kk(firstO=0) first, waves 4-7 kk(firstO=16384)
  const int h0 = firstO;
  const int h1 = 16384 - firstO;
  half16(lds + curO + h0, lds + curO + 32768 + h0, aoff0, boff0, acc);
  half16(lds + curO + h1, lds + curO + 32768 + h1, aoff0, boff0, acc);
  if (t + 1 < NT) {
    asm volatile("s_waitcnt vmcnt(0)" ::: "memory");  // issued a full tile ago
  }
  SB0;
  __builtin_amdgcn_s_barrier();
  SB0;
}

template <int EPI>
__global__ __launch_bounds__(512, 2) void gemm256(
    const bf16_t* __restrict__ A, const bf16_t* __restrict__ Bt,
    const float* __restrict__ bias, void* __restrict__ Cout, int N, int K) {
  extern __shared__ char lds[];
  const int tid = threadIdx.x;
  const int lane = tid & 63;
  const int wave = tid >> 6;
  const int wm = (wave >> 2) * 128;  // 2 M-waves
  const int wn = (wave & 3) * 64;    // 4 N-waves
  const int l15 = lane & 15;
  // swizzled ds_read slot: (logical k-quad lane>>4) ^ ((row>>1)&3)
  const int kqs = ((lane >> 4) ^ ((lane >> 1) & 3)) << 4;
  const int aoff0 = (wm + l15) * 64 + kqs;
  const int boff0 = (wn + l15) * 64 + kqs;
  const int firstO = (wave < 4) ? 0 : 16384;  // anti-phase k-half order

  // XCD-aware bijective swizzle (nwg % 8 == 0 for all our grids)
  const int gx = gridDim.x;
  int id = blockIdx.y * gx + blockIdx.x;
  const int cpx = (gx * (int)gridDim.y) >> 3;
  id = (id & 7) * cpx + (id >> 3);
  const int bm = (id / gx) * 256;
  const int bn = (id % gx) * 256;

  // staging source: row tid>>2 (+128 for 2nd issue), inverse-swizzled k-slot
  const int srow = tid >> 2;
  const int ss8 = ((tid & 3) ^ ((tid >> 3) & 3)) * 8;
  const bf16_t* gA = A + (size_t)(bm + srow) * K + ss8;
  const bf16_t* gB = Bt + (size_t)(bn + srow) * K + ss8;

  const int NT = K >> 6;  // 32 or 64, always even

  floatx4 acc[8][4] = {};

  // ---- prologue: stage tile0; publish
  stage_half(gA, K, lds + 0, tid);
  stage_half(gA + 32, K, lds + 16384, tid);
  stage_half(gB, K, lds + 32768, tid);
  stage_half(gB + 32, K, lds + 49152, tid);
  asm volatile("s_waitcnt vmcnt(0)" ::: "memory");
  __builtin_amdgcn_s_barrier();
  SB0;

  for (int t = 0; t < NT; t += 2) {
    ktile<0>(t, NT, K, gA, gB, lds, tid, aoff0, boff0, firstO, acc);
    ktile<1>(t + 1, NT, K, gA, gB, lds, tid, aoff0, boff0, firstO, acc);
  }

  // epilogue (swapped-operand layout, R2-verified): acc[i][j] lane l reg r =
  //   C[bm + wm + i*16 + (l&15)][bn + wn + j*16 + (l>>4)*4 + r]
  const int kq4 = lane >> 4;
  const int row00 = bm + wm + l15;
  const int colq = bn + wn + kq4 * 4;
  float4 b4[4];
#pragma unroll
  for (int j = 0; j < 4; ++j) b4[j] = *(const float4*)&bias[colq + j * 16];
#pragma unroll
  for (int i = 0; i < 8; ++i) {
    const size_t rbase = (size_t)(row00 + i * 16) * N;
#pragma unroll
    for (int j = 0; j < 4; ++j) {
      float x0 = acc[i][j][0] + b4[j].x;
      float x1 = acc[i][j][1] + b4[j].y;
      float x2 = acc[i][j][2] + b4[j].z;
      float x3 = acc[i][j][3] + b4[j].w;
      if (EPI == 0) {
        x0 = fmaxf(x0, 0.f);
        x1 = fmaxf(x1, 0.f);
        x2 = fmaxf(x2, 0.f);
        x3 = fmaxf(x3, 0.f);
        bf16x4 o;
        o[0] = (bf16_t)x0; o[1] = (bf16_t)x1; o[2] = (bf16_t)x2; o[3] = (bf16_t)x3;
        *(bf16x4*)((bf16_t*)Cout + rbase + colq + j * 16) = o;
      } else {
        float4 o = make_float4(x0, x1, x2, x3);
        *(float4*)((float*)Cout + rbase + colq + j * 16) = o;
      }
    }
  }
}

// ---------------------------------------------------------------------------
extern "C" void kernel_launch(void* const* d_in, const int* in_sizes, int n_in,
                              void* d_out, int out_size, void* d_ws, size_t ws_size,
                              hipStream_t stream) {
  const float* x = (const float*)d_in[0];
  const float *Mm[4], *uu[4], *vv[4], *ee[4];
  for (int i = 0; i < 4; ++i) {
    Mm[i] = (const float*)d_in[1 + 4 * i];
    uu[i] = (const float*)d_in[2 + 4 * i];
    vv[i] = (const float*)d_in[3 + 4 * i];
    ee[i] = (const float*)d_in[4 + 4 * i];
  }

  // workspace layout (≈224 MiB):
  //   Wt0 [4096,2048] bf16 | Wt1 [4096,4096] | Wt2 [4096,4096] | Wt3 [2048,4096]
  //   bias0..3 fp32 | hA (8192x4096 bf16) | hB (8192x4096 bf16)
  char* ws = (char*)d_ws;
  bf16_t* Wt0 = (bf16_t*)ws;
  bf16_t* Wt1 = (bf16_t*)(ws + 16777216);
  bf16_t* Wt2 = (bf16_t*)(ws + 16777216 + 33554432);
  bf16_t* Wt3 = (bf16_t*)(ws + 16777216 + 2u * 33554432);
  char* bptr = ws + 2u * 16777216 + 2u * 33554432;
  float* bias0 = (float*)(bptr);
  float* bias1 = (float*)(bptr + 16384);
  float* bias2 = (float*)(bptr + 32768);
  float* bias3 = (float*)(bptr + 49152);
  char* act = bptr + 65536;
  bf16_t* hA = (bf16_t*)act;
  bf16_t* hB = (bf16_t*)(act + 67108864);
  bf16_t* xb = (bf16_t*)d_out;  // dead until final GEMM overwrites d_out

  static bool attr_set = false;
  if (!attr_set) {
    (void)hipFuncSetAttribute(reinterpret_cast<const void*>(&gemm256<0>),
                              hipFuncAttributeMaxDynamicSharedMemorySize, 131072);
    (void)hipFuncSetAttribute(reinterpret_cast<const void*>(&gemm256<1>),
                              hipFuncAttributeMaxDynamicSharedMemorySize, 131072);
    attr_set = true;
  }

  // --- fused prep: 1 launch (cvt 16384 | wt 49152 | bias 56) ---
  PrepArgs pa;
  pa.x = x;
  pa.xb = xb;
  for (int i = 0; i < 4; ++i) {
    pa.M[i] = Mm[i]; pa.u[i] = uu[i]; pa.v[i] = vv[i]; pa.e[i] = ee[i];
  }
  pa.Wt[0] = Wt0; pa.Wt[1] = Wt1; pa.Wt[2] = Wt2; pa.Wt[3] = Wt3;
  pa.bias[0] = bias0; pa.bias[1] = bias1; pa.bias[2] = bias2; pa.bias[3] = bias3;
  prep_all<<<16384 + 49152 + 56, dim3(32, 8), 0, stream>>>(pa);

  // --- chained GEMMs: 256^2, 16x16x32 MFMA, anti-phase wave schedule ---
  gemm256<0><<<dim3(16, 32), 512, 131072, stream>>>(xb, Wt0, bias0, hA, 4096, 2048);
  gemm256<0><<<dim3(16, 32), 512, 131072, stream>>>(hA, Wt1, bias1, hB, 4096, 4096);
  gemm256<0><<<dim3(16, 32), 512, 131072, stream>>>(hB, Wt2, bias2, hA, 4096, 4096);
  gemm256<1><<<dim3(8, 32), 512, 131072, stream>>>(hA, Wt3, bias3, d_out, 2048, 4096);
}